// Round 5
// baseline (26241.562 us; speedup 1.0000x reference)
//
#include <hip/hip_runtime.h>

typedef __attribute__((ext_vector_type(8))) short short8v;
typedef __attribute__((ext_vector_type(4))) float f32x4;

#define MFMA(a,b,c) __builtin_amdgcn_mfma_f32_16x16x32_bf16((a),(b),(c),0,0,0)

__device__ __forceinline__ float rcpf_(float x){ return __builtin_amdgcn_rcpf(x); }
__device__ __forceinline__ float sigf(float x){ return rcpf_(1.0f + __expf(-x)); }
__device__ __forceinline__ float tanhfast(float x){ return fmaf(-2.0f, rcpf_(1.0f + __expf(2.0f*x)), 1.0f); }
__device__ __forceinline__ float bf2f(unsigned short u){ union{unsigned int i; float f;} v; v.i = ((unsigned int)u)<<16; return v.f; }
__device__ __forceinline__ float u2f(unsigned int i){ union{unsigned int i; float f;} v; v.i = i; return v.f; }
__device__ __forceinline__ unsigned short f2bf(float f){ union{float f; unsigned int i;} v; v.f=f; unsigned int x = v.i + 0x7fffu + ((v.i>>16)&1u); return (unsigned short)(x>>16); }
__device__ __forceinline__ float4 ld4(const float* p){ return *(const float4*)p; }

// ============ prep: weight converts (unchanged from round-3, proven) ============
__global__ __launch_bounds__(256) void k_w1(const float* __restrict__ iw1, const float* __restrict__ hw1,
                                            ushort* __restrict__ w1b){
  int idx4 = (blockIdx.x*256 + threadIdx.x) * 4;       // 4096*1536
  int n = idx4 / 1536, k = idx4 % 1536;
  float4 v = (k < 512) ? *(const float4*)(iw1 + n*512 + k)
                       : *(const float4*)(hw1 + n*1024 + (k - 512));
  ushort4 o; o.x=f2bf(v.x); o.y=f2bf(v.y); o.z=f2bf(v.z); o.w=f2bf(v.w);
  *(ushort4*)(w1b + idx4) = o;
}
__global__ __launch_bounds__(256) void k_w2(const float* __restrict__ h2a, const float* __restrict__ hw2,
                                            ushort* __restrict__ w2b){
  int idx4 = (blockIdx.x*256 + threadIdx.x) * 4;       // 5120*1024
  int n = idx4 >> 10, k = idx4 & 1023;
  float4 v = (n < 1024) ? *(const float4*)(h2a + n*1024 + k)
                        : *(const float4*)(hw2 + (n-1024)*1024 + k);
  ushort4 o; o.x=f2bf(v.x); o.y=f2bf(v.y); o.z=f2bf(v.z); o.w=f2bf(v.w);
  *(ushort4*)(w2b + idx4) = o;
}
__global__ __launch_bounds__(256) void k_w3(const float* __restrict__ iw2, ushort* __restrict__ w3b){
  int idx4 = (blockIdx.x*256 + threadIdx.x) * 4;       // 4096*1024
  float4 v = *(const float4*)(iw2 + idx4);
  ushort4 o; o.x=f2bf(v.x); o.y=f2bf(v.y); o.z=f2bf(v.z); o.w=f2bf(v.w);
  *(ushort4*)(w3b + idx4) = o;
}
// ctxb[b][s][c] bf16 from ctx[s][b][c]
__global__ __launch_bounds__(256) void k_ctxT(const float* __restrict__ ctx, ushort* __restrict__ ctxb){
  int idx4 = (blockIdx.x*256 + threadIdx.x) * 4;       // 64*256*1024
  int c = idx4 & 1023, s = (idx4 >> 10) & 255, b = idx4 >> 18;
  float4 v = *(const float4*)(ctx + (s*64 + b)*1024 + c);
  ushort4 o; o.x=f2bf(v.x); o.y=f2bf(v.y); o.z=f2bf(v.z); o.w=f2bf(v.w);
  *(ushort4*)(ctxb + idx4) = o;
}
// xb[t][b][k] bf16 from input[b][t][k]
__global__ __launch_bounds__(256) void k_xb(const float* __restrict__ inp, ushort* __restrict__ xb){
  int idx4 = (blockIdx.x*256 + threadIdx.x) * 4;       // 256*64*512
  int k = idx4 & 511, b = (idx4 >> 9) & 63, t = idx4 >> 15;
  float4 v = *(const float4*)(inp + (b*256 + t)*512 + k);
  ushort4 o; o.x=f2bf(v.x); o.y=f2bf(v.y); o.z=f2bf(v.z); o.w=f2bf(v.w);
  *(ushort4*)(xb + idx4) = o;
}
// i2aT[n][k] bf16 from i2a[k][n]
__global__ __launch_bounds__(256) void k_i2aT(const float* __restrict__ i2a, ushort* __restrict__ i2aT){
  int idx = blockIdx.x*256 + threadIdx.x;              // 512*1024
  int n = idx & 1023, k = idx >> 10;
  i2aT[n*512 + k] = f2bf(i2a[k*1024 + n]);
}
__global__ __launch_bounds__(256) void k_cvthx(const float* __restrict__ hx, ushort* __restrict__ hxbbf){
  int i4 = (blockIdx.x*256 + threadIdx.x)*4;
  float4 v = ld4(hx + i4);
  ushort4 o; o.x=f2bf(v.x); o.y=f2bf(v.y); o.z=f2bf(v.z); o.w=f2bf(v.w);
  *(ushort4*)(hxbbf + i4) = o;
}

// ============ prep: pc GEMM (f32 in, bf16 out) ============
__global__ __launch_bounds__(256) void k_pc(const float* __restrict__ ctxp, const float* __restrict__ c2a,
                                            const float* __restrict__ bc, ushort* __restrict__ pcb){
  __shared__ __align__(16) float As[32][68];
  __shared__ __align__(16) float Bs[32][68];
  const int tid = threadIdx.x;
  const int m0 = blockIdx.x * 64;
  const int n0 = blockIdx.y * 64;
  const int tx = tid & 15, ty = tid >> 4;
  float acc[4][4] = {};
  for (int k0 = 0; k0 < 1024; k0 += 32){
#pragma unroll
    for (int l = 0; l < 8; ++l){
      int idx = l*256 + tid; int m = idx >> 5, k = idx & 31;
      As[k][m] = ctxp[(m0+m)*1024 + k0 + k];
    }
#pragma unroll
    for (int l = 0; l < 8; ++l){
      int idx = l*256 + tid; int k = idx >> 6, n = idx & 63;
      Bs[k][n] = c2a[(k0+k)*1024 + n0 + n];
    }
    __syncthreads();
#pragma unroll
    for (int k = 0; k < 32; ++k){
      float4 a4 = *(const float4*)&As[k][4*ty];
      float4 b4 = *(const float4*)&Bs[k][4*tx];
      float av[4] = {a4.x, a4.y, a4.z, a4.w};
      float bv[4] = {b4.x, b4.y, b4.z, b4.w};
#pragma unroll
      for (int i = 0; i < 4; ++i)
#pragma unroll
        for (int j = 0; j < 4; ++j) acc[i][j] = fmaf(av[i], bv[j], acc[i][j]);
    }
    __syncthreads();
  }
#pragma unroll
  for (int i = 0; i < 4; ++i){
    int m = m0 + 4*ty + i;
    int n = n0 + 4*tx;
    ushort4 o;
    o.x = f2bf(acc[i][0] + bc[n]);
    o.y = f2bf(acc[i][1] + bc[n+1]);
    o.z = f2bf(acc[i][2] + bc[n+2]);
    o.w = f2bf(acc[i][3] + bc[n+3]);
    *(ushort4*)(pcb + m*1024 + n) = o;
  }
}

// ============ K_A: gates1 MFMA + LSTM1 pointwise, fused ============
// 64 blocks x 512 thr (8 waves): wave w -> gate g=w&3, K-half kh=w>>2 (K=1536 -> 768 each)
// block j covers h-cols [16j,16j+16); each wave: 4 row-strips of 16 (all 64 batch rows)
__global__ __launch_bounds__(512) void k_step1(const ushort* __restrict__ xb, const ushort* __restrict__ hxbf,
                                               const ushort* __restrict__ w1b,
                                               const float* __restrict__ ib1, const float* __restrict__ hb1,
                                               const float* __restrict__ cxb,
                                               float* __restrict__ cym, ushort* __restrict__ hybf, int t){
  __shared__ float lds[2][4][64][17];
  const int tid = threadIdx.x;
  const int lane = tid & 63;
  const int w = tid >> 6;
  const int g = w & 3;
  const int kh = w >> 2;
  const int j = blockIdx.x;
  const int ncol = g*1024 + j*16 + (lane & 15);
  const int ko = (lane >> 4) << 3;
  const int arow = lane & 15;
  const ushort* wp = w1b + ncol*1536 + kh*768 + ko;
  f32x4 a0 = {0.f,0.f,0.f,0.f}, a1 = a0, a2 = a0, a3 = a0;
  if (kh == 0){
    const ushort* xp = xb + (t*64 + arow)*512 + ko;
#pragma unroll
    for (int it = 0; it < 16; ++it){
      short8v bf = *(const short8v*)(wp + it*32);
      a0 = MFMA(*(const short8v*)(xp + it*32), bf, a0);
      a1 = MFMA(*(const short8v*)(xp + it*32 + 16*512), bf, a1);
      a2 = MFMA(*(const short8v*)(xp + it*32 + 32*512), bf, a2);
      a3 = MFMA(*(const short8v*)(xp + it*32 + 48*512), bf, a3);
    }
    const ushort* hp = hxbf + arow*1024 + ko;
#pragma unroll
    for (int it = 0; it < 8; ++it){
      short8v bf = *(const short8v*)(wp + (16+it)*32);
      a0 = MFMA(*(const short8v*)(hp + it*32), bf, a0);
      a1 = MFMA(*(const short8v*)(hp + it*32 + 16*1024), bf, a1);
      a2 = MFMA(*(const short8v*)(hp + it*32 + 32*1024), bf, a2);
      a3 = MFMA(*(const short8v*)(hp + it*32 + 48*1024), bf, a3);
    }
  } else {
    const ushort* hp = hxbf + arow*1024 + 256 + ko;
#pragma unroll
    for (int it = 0; it < 24; ++it){
      short8v bf = *(const short8v*)(wp + it*32);
      a0 = MFMA(*(const short8v*)(hp + it*32), bf, a0);
      a1 = MFMA(*(const short8v*)(hp + it*32 + 16*1024), bf, a1);
      a2 = MFMA(*(const short8v*)(hp + it*32 + 32*1024), bf, a2);
      a3 = MFMA(*(const short8v*)(hp + it*32 + 48*1024), bf, a3);
    }
  }
  {
    const int ccol = lane & 15;
    const int rb = (lane >> 4) * 4;
#pragma unroll
    for (int r = 0; r < 4; ++r){
      lds[kh][g][rb + r][ccol]      = a0[r];
      lds[kh][g][16 + rb + r][ccol] = a1[r];
      lds[kh][g][32 + rb + r][ccol] = a2[r];
      lds[kh][g][48 + rb + r][ccol] = a3[r];
    }
  }
  __syncthreads();
  // pointwise: 2 consecutive h-cols per thread
  const int e = tid * 2;
  const int row = e >> 4;
  const int c0 = e & 15;
  const int h = j*16 + c0;
#pragma unroll
  for (int u = 0; u < 2; ++u){
    int c = c0 + u, hh = h + u;
    float gi = lds[0][0][row][c] + lds[1][0][row][c] + ib1[hh]        + hb1[hh];
    float gf = lds[0][1][row][c] + lds[1][1][row][c] + ib1[1024+hh]   + hb1[1024+hh];
    float gg = lds[0][2][row][c] + lds[1][2][row][c] + ib1[2048+hh]   + hb1[2048+hh];
    float go = lds[0][3][row][c] + lds[1][3][row][c] + ib1[3072+hh]   + hb1[3072+hh];
    float cc = sigf(gf)*cxb[row*1024 + hh] + sigf(gi)*tanhfast(gg);
    cym[row*1024 + hh] = cc;
    hybf[row*1024 + hh] = f2bf(sigf(go)*tanhfast(cc));
  }
}

// ============ K_B: hyproj MFMA (full K per wave) ============
// 320 blocks x 256 thr: block = 16 cols of N=5120; wave = one 16-row strip.
// cols<1024 also fold in x_t @ i2a (projected_input).
__global__ __launch_bounds__(256) void k_hyproj(const ushort* __restrict__ hybf, const ushort* __restrict__ w2b,
                                                const ushort* __restrict__ xb, const ushort* __restrict__ i2aT,
                                                float* __restrict__ hyp, int t){
  const int lane = threadIdx.x & 63;
  const int strip = threadIdx.x >> 6;
  const int ntile = blockIdx.x * 16;
  const int ncol = ntile + (lane & 15);
  const int ko = (lane >> 4) << 3;
  const int arow = strip*16 + (lane & 15);
  const ushort* wp = w2b + ncol*1024 + ko;
  const ushort* hp = hybf + arow*1024 + ko;
  f32x4 acc = {0.f,0.f,0.f,0.f};
#pragma unroll
  for (int it = 0; it < 32; ++it)
    acc = MFMA(*(const short8v*)(hp + it*32), *(const short8v*)(wp + it*32), acc);
  if (ntile < 1024){
    const ushort* ip = i2aT + ncol*512 + ko;
    const ushort* xp = xb + (t*64 + arow)*512 + ko;
#pragma unroll
    for (int it = 0; it < 16; ++it)
      acc = MFMA(*(const short8v*)(xp + it*32), *(const short8v*)(ip + it*32), acc);
  }
  float* op = hyp + ncol;
  const int rb = strip*16 + (lane >> 4)*4;
#pragma unroll
  for (int r = 0; r < 4; ++r) op[(rb + r)*5120] = acc[r];
}

// ============ K_C: logits ============
// 256 blocks x 256 thr: block = (b, s-quarter). q[b], r hoisted to registers.
__global__ __launch_bounds__(256) void k_logits(const ushort* __restrict__ pcb, const float* __restrict__ hyp,
                                                const float* __restrict__ r2a, float* __restrict__ logits){
  const int b = blockIdx.x >> 2;
  const int sq = blockIdx.x & 3;
  const int w = threadIdx.x >> 6, lane = threadIdx.x & 63;
  const float* qp = hyp + b*5120 + lane*16;
  const float* rp = r2a + lane*16;
  float q[16], r[16];
#pragma unroll
  for (int i = 0; i < 4; ++i){
    float4 qv = ld4(qp + i*4);
    float4 rv = ld4(rp + i*4);
    q[4*i]=qv.x; q[4*i+1]=qv.y; q[4*i+2]=qv.z; q[4*i+3]=qv.w;
    r[4*i]=rv.x; r[4*i+1]=rv.y; r[4*i+2]=rv.z; r[4*i+3]=rv.w;
  }
#pragma unroll 4
  for (int pi = 0; pi < 16; ++pi){
    const int s = sq*64 + w*16 + pi;
    const ushort* pp = pcb + (s*64 + b)*1024 + lane*16;
    uint4 v0 = *(const uint4*)pp;
    uint4 v1 = *(const uint4*)(pp + 8);
    float acc;
    acc  = tanhfast(u2f(v0.x << 16)         + q[0])  * r[0];
    acc  = fmaf(tanhfast(u2f(v0.x & 0xffff0000u) + q[1]),  r[1],  acc);
    acc  = fmaf(tanhfast(u2f(v0.y << 16)         + q[2]),  r[2],  acc);
    acc  = fmaf(tanhfast(u2f(v0.y & 0xffff0000u) + q[3]),  r[3],  acc);
    acc  = fmaf(tanhfast(u2f(v0.z << 16)         + q[4]),  r[4],  acc);
    acc  = fmaf(tanhfast(u2f(v0.z & 0xffff0000u) + q[5]),  r[5],  acc);
    acc  = fmaf(tanhfast(u2f(v0.w << 16)         + q[6]),  r[6],  acc);
    acc  = fmaf(tanhfast(u2f(v0.w & 0xffff0000u) + q[7]),  r[7],  acc);
    acc  = fmaf(tanhfast(u2f(v1.x << 16)         + q[8]),  r[8],  acc);
    acc  = fmaf(tanhfast(u2f(v1.x & 0xffff0000u) + q[9]),  r[9],  acc);
    acc  = fmaf(tanhfast(u2f(v1.y << 16)         + q[10]), r[10], acc);
    acc  = fmaf(tanhfast(u2f(v1.y & 0xffff0000u) + q[11]), r[11], acc);
    acc  = fmaf(tanhfast(u2f(v1.z << 16)         + q[12]), r[12], acc);
    acc  = fmaf(tanhfast(u2f(v1.z & 0xffff0000u) + q[13]), r[13], acc);
    acc  = fmaf(tanhfast(u2f(v1.w << 16)         + q[14]), r[14], acc);
    acc  = fmaf(tanhfast(u2f(v1.w & 0xffff0000u) + q[15]), r[15], acc);
#pragma unroll
    for (int off = 32; off; off >>= 1) acc += __shfl_xor(acc, off);
    if (lane == 0) logits[b*256 + s] = acc;
  }
}

// ============ K_D: softmax + full weighted-context (writes wctxbf directly) ============
// 256 blocks x 256 thr: block = (b, c-quarter); thread owns one c, loops all 256 s.
__global__ __launch_bounds__(256) void k_attnout(const float* __restrict__ logits, const ushort* __restrict__ ctxb,
                                                 ushort* __restrict__ wctxbf){
  __shared__ float red[256];
  __shared__ float al[256];
  const int bi = blockIdx.x >> 2, cq = blockIdx.x & 3;
  const int tid = threadIdx.x;
  float l = logits[bi*256 + tid];
  red[tid] = l; __syncthreads();
  for (int s = 128; s; s >>= 1){ if (tid < s) red[tid] = fmaxf(red[tid], red[tid+s]); __syncthreads(); }
  float mx = red[0]; __syncthreads();
  float e = __expf(l - mx);
  al[tid] = e; red[tid] = e; __syncthreads();
  for (int s = 128; s; s >>= 1){ if (tid < s) red[tid] += red[tid+s]; __syncthreads(); }
  float inv = rcpf_(red[0]);
  const int c = cq*256 + tid;
  const ushort* cp = ctxb + bi*256*1024 + c;
  float acc = 0.0f;
#pragma unroll 8
  for (int s = 0; s < 256; ++s)
    acc = fmaf(al[s], bf2f(cp[s*1024]), acc);
  wctxbf[bi*1024 + c] = f2bf(acc * inv);
}

// ============ K_E: gates2 MFMA + LSTM2 pointwise, fused ============
// 64 blocks x 512 thr: wave w -> gate g=w&3, K-half kh=w>>2 (K=1024 -> 512 each)
__global__ __launch_bounds__(512) void k_step2(const ushort* __restrict__ wctxbf, const ushort* __restrict__ w3b,
                                               const float* __restrict__ hyp,
                                               const float* __restrict__ ib2, const float* __restrict__ hb2,
                                               const float* __restrict__ cym,
                                               float* __restrict__ out, float* __restrict__ hxb,
                                               ushort* __restrict__ hxbbf, float* __restrict__ cxb, int t){
  __shared__ float lds[2][4][64][17];
  const int tid = threadIdx.x;
  const int lane = tid & 63;
  const int w = tid >> 6;
  const int g = w & 3;
  const int kh = w >> 2;
  const int j = blockIdx.x;
  const int ncol = g*1024 + j*16 + (lane & 15);
  const int ko = (lane >> 4) << 3;
  const int arow = lane & 15;
  const ushort* wp = w3b + ncol*1024 + kh*512 + ko;
  const ushort* ap = wctxbf + arow*1024 + kh*512 + ko;
  f32x4 a0 = {0.f,0.f,0.f,0.f}, a1 = a0, a2 = a0, a3 = a0;
#pragma unroll
  for (int it = 0; it < 16; ++it){
    short8v bf = *(const short8v*)(wp + it*32);
    a0 = MFMA(*(const short8v*)(ap + it*32), bf, a0);
    a1 = MFMA(*(const short8v*)(ap + it*32 + 16*1024), bf, a1);
    a2 = MFMA(*(const short8v*)(ap + it*32 + 32*1024), bf, a2);
    a3 = MFMA(*(const short8v*)(ap + it*32 + 48*1024), bf, a3);
  }
  {
    const int ccol = lane & 15;
    const int rb = (lane >> 4) * 4;
#pragma unroll
    for (int r = 0; r < 4; ++r){
      lds[kh][g][rb + r][ccol]      = a0[r];
      lds[kh][g][16 + rb + r][ccol] = a1[r];
      lds[kh][g][32 + rb + r][ccol] = a2[r];
      lds[kh][g][48 + rb + r][ccol] = a3[r];
    }
  }
  __syncthreads();
  const int e = tid * 2;
  const int row = e >> 4;
  const int c0 = e & 15;
#pragma unroll
  for (int u = 0; u < 2; ++u){
    int c = c0 + u;
    int hh = j*16 + c;
    const float* g2 = hyp + row*5120 + 1024;
    float gi = lds[0][0][row][c] + lds[1][0][row][c] + g2[hh]        + ib2[hh]      + hb2[hh];
    float gf = lds[0][1][row][c] + lds[1][1][row][c] + g2[1024+hh]   + ib2[1024+hh] + hb2[1024+hh];
    float gg = lds[0][2][row][c] + lds[1][2][row][c] + g2[2048+hh]   + ib2[2048+hh] + hb2[2048+hh];
    float go = lds[0][3][row][c] + lds[1][3][row][c] + g2[3072+hh]   + ib2[3072+hh] + hb2[3072+hh];
    float cc = sigf(gf)*cym[row*1024 + hh] + sigf(gi)*tanhfast(gg);
    float hv = sigf(go)*tanhfast(cc);
    out[t*65536 + row*1024 + hh] = hv;
    hxb[row*1024 + hh] = hv;
    cxb[row*1024 + hh] = cc;
    hxbbf[row*1024 + hh] = f2bf(hv);
  }
}

extern "C" void kernel_launch(void* const* d_in, const int* in_sizes, int n_in,
                              void* d_out, int out_size, void* d_ws, size_t ws_size,
                              hipStream_t stream) {
  const float* input = (const float*)d_in[0];
  const float* hx    = (const float*)d_in[1];
  const float* cx    = (const float*)d_in[2];
  const float* ctxp  = (const float*)d_in[3];
  const float* iw1   = (const float*)d_in[4];
  const float* hw1   = (const float*)d_in[5];
  const float* ib1   = (const float*)d_in[6];
  const float* hb1   = (const float*)d_in[7];
  const float* iw2   = (const float*)d_in[8];
  const float* hw2   = (const float*)d_in[9];
  const float* ib2   = (const float*)d_in[10];
  const float* hb2   = (const float*)d_in[11];
  const float* c2a   = (const float*)d_in[12];
  const float* b_c2a = (const float*)d_in[13];
  const float* h2a   = (const float*)d_in[14];
  const float* i2a   = (const float*)d_in[15];
  const float* r2a   = (const float*)d_in[16];
  float* out = (float*)d_out;

  char* base = (char*)d_ws;
  ushort* pcb    = (ushort*)(base);                     // 33,554,432
  ushort* ctxb   = (ushort*)(base + 33554432);          // 33,554,432
  ushort* xb     = (ushort*)(base + 67108864);          // 16,777,216
  ushort* w1b    = (ushort*)(base + 83886080);          // 12,582,912
  ushort* w2b    = (ushort*)(base + 96468992);          // 10,485,760
  ushort* w3b    = (ushort*)(base + 106954752);         //  8,388,608
  ushort* i2aT   = (ushort*)(base + 115343360);         //  1,048,576
  float*  hyp    = (float*)(base + 116391936);          //  1,310,720
  float*  cym    = (float*)(base + 117702656);          //    262,144
  float*  hxb    = (float*)(base + 117964800);          //    262,144
  float*  cxb    = (float*)(base + 118226944);          //    262,144
  ushort* hybf   = (ushort*)(base + 118489088);         //    131,072
  ushort* hxbbf  = (ushort*)(base + 118620160);         //    131,072
  ushort* wctxbf = (ushort*)(base + 118751232);         //    131,072
  float*  logits = (float*)(base + 118882304);          //     65,536  (end 118,947,840)

  hipMemcpyAsync(hxb, hx, 262144, hipMemcpyDeviceToDevice, stream);
  hipMemcpyAsync(cxb, cx, 262144, hipMemcpyDeviceToDevice, stream);

  k_cvthx<<<64,   256, 0, stream>>>(hx, hxbbf);
  k_w1  <<<6144,  256, 0, stream>>>(iw1, hw1, w1b);
  k_w2  <<<5120,  256, 0, stream>>>(h2a, hw2, w2b);
  k_w3  <<<4096,  256, 0, stream>>>(iw2, w3b);
  k_ctxT<<<16384, 256, 0, stream>>>(ctxp, ctxb);
  k_xb  <<<8192,  256, 0, stream>>>(input, xb);
  k_i2aT<<<2048,  256, 0, stream>>>(i2a, i2aT);
  k_pc  <<<dim3(256,16), 256, 0, stream>>>(ctxp, c2a, b_c2a, pcb);

  for (int t = 0; t < 256; ++t){
    k_step1  <<<64,  512, 0, stream>>>(xb, hxbbf, w1b, ib1, hb1, cxb, cym, hybf, t);
    k_hyproj <<<320, 256, 0, stream>>>(hybf, w2b, xb, i2aT, hyp, t);
    k_logits <<<256, 256, 0, stream>>>(pcb, hyp, r2a, logits);
    k_attnout<<<256, 256, 0, stream>>>(logits, ctxb, wctxbf);
    k_step2  <<<64,  512, 0, stream>>>(wctxbf, w3b, hyp, ib2, hb2, cym, out, hxb, hxbbf, cxb, t);
  }

  hipMemcpyAsync(out + 16777216,         hxb, 262144, hipMemcpyDeviceToDevice, stream);
  hipMemcpyAsync(out + 16777216 + 65536, cxb, 262144, hipMemcpyDeviceToDevice, stream);
}

// Round 6
// 22547.948 us; speedup vs baseline: 1.1638x; 1.1638x over previous
//
#include <hip/hip_runtime.h>

typedef __attribute__((ext_vector_type(8))) short short8v;
typedef __attribute__((ext_vector_type(4))) float f32x4;

#define MFMA(a,b,c) __builtin_amdgcn_mfma_f32_16x16x32_bf16((a),(b),(c),0,0,0)

__device__ __forceinline__ float rcpf_(float x){ return __builtin_amdgcn_rcpf(x); }
__device__ __forceinline__ float sigf(float x){ return rcpf_(1.0f + __expf(-x)); }
__device__ __forceinline__ float tanhfast(float x){ return fmaf(-2.0f, rcpf_(1.0f + __expf(2.0f*x)), 1.0f); }
__device__ __forceinline__ float bf2f(unsigned short u){ union{unsigned int i; float f;} v; v.i = ((unsigned int)u)<<16; return v.f; }
__device__ __forceinline__ float u2f(unsigned int i){ union{unsigned int i; float f;} v; v.i = i; return v.f; }
__device__ __forceinline__ unsigned short f2bf(float f){ union{float f; unsigned int i;} v; v.f=f; unsigned int x = v.i + 0x7fffu + ((v.i>>16)&1u); return (unsigned short)(x>>16); }
__device__ __forceinline__ float4 ld4(const float* p){ return *(const float4*)p; }

// ============ prep kernels ============
__global__ __launch_bounds__(256) void k_w1(const float* __restrict__ iw1, const float* __restrict__ hw1,
                                            ushort* __restrict__ w1b){
  int idx4 = (blockIdx.x*256 + threadIdx.x) * 4;       // 4096*1536
  int n = idx4 / 1536, k = idx4 % 1536;
  float4 v = (k < 512) ? *(const float4*)(iw1 + n*512 + k)
                       : *(const float4*)(hw1 + n*1024 + (k - 512));
  ushort4 o; o.x=f2bf(v.x); o.y=f2bf(v.y); o.z=f2bf(v.z); o.w=f2bf(v.w);
  *(ushort4*)(w1b + idx4) = o;
}
__global__ __launch_bounds__(256) void k_w2(const float* __restrict__ h2a, const float* __restrict__ hw2,
                                            ushort* __restrict__ w2b){
  int idx4 = (blockIdx.x*256 + threadIdx.x) * 4;       // 5120*1024
  int n = idx4 >> 10, k = idx4 & 1023;
  float4 v = (n < 1024) ? *(const float4*)(h2a + n*1024 + k)
                        : *(const float4*)(hw2 + (n-1024)*1024 + k);
  ushort4 o; o.x=f2bf(v.x); o.y=f2bf(v.y); o.z=f2bf(v.z); o.w=f2bf(v.w);
  *(ushort4*)(w2b + idx4) = o;
}
__global__ __launch_bounds__(256) void k_w3(const float* __restrict__ iw2, ushort* __restrict__ w3b){
  int idx4 = (blockIdx.x*256 + threadIdx.x) * 4;       // 4096*1024
  float4 v = *(const float4*)(iw2 + idx4);
  ushort4 o; o.x=f2bf(v.x); o.y=f2bf(v.y); o.z=f2bf(v.z); o.w=f2bf(v.w);
  *(ushort4*)(w3b + idx4) = o;
}
// ctxb[b][s][c] bf16 from ctx[s][b][c]
__global__ __launch_bounds__(256) void k_ctxT(const float* __restrict__ ctx, ushort* __restrict__ ctxb){
  int idx4 = (blockIdx.x*256 + threadIdx.x) * 4;       // 64*256*1024
  int c = idx4 & 1023, s = (idx4 >> 10) & 255, b = idx4 >> 18;
  float4 v = *(const float4*)(ctx + (s*64 + b)*1024 + c);
  ushort4 o; o.x=f2bf(v.x); o.y=f2bf(v.y); o.z=f2bf(v.z); o.w=f2bf(v.w);
  *(ushort4*)(ctxb + idx4) = o;
}
// xb[t][b][k] bf16 from input[b][t][k]
__global__ __launch_bounds__(256) void k_xb(const float* __restrict__ inp, ushort* __restrict__ xb){
  int idx4 = (blockIdx.x*256 + threadIdx.x) * 4;       // 256*64*512
  int k = idx4 & 511, b = (idx4 >> 9) & 63, t = idx4 >> 15;
  float4 v = *(const float4*)(inp + (b*256 + t)*512 + k);
  ushort4 o; o.x=f2bf(v.x); o.y=f2bf(v.y); o.z=f2bf(v.z); o.w=f2bf(v.w);
  *(ushort4*)(xb + idx4) = o;
}
// i2aT[n][k] bf16 from i2a[k][n]
__global__ __launch_bounds__(256) void k_i2aT(const float* __restrict__ i2a, ushort* __restrict__ i2aT){
  int idx = blockIdx.x*256 + threadIdx.x;              // 512*1024
  int n = idx & 1023, k = idx >> 10;
  i2aT[n*512 + k] = f2bf(i2a[k*1024 + n]);
}
__global__ __launch_bounds__(256) void k_cvthx(const float* __restrict__ hx, ushort* __restrict__ hxbbf){
  int i4 = (blockIdx.x*256 + threadIdx.x)*4;
  float4 v = ld4(hx + i4);
  ushort4 o; o.x=f2bf(v.x); o.y=f2bf(v.y); o.z=f2bf(v.z); o.w=f2bf(v.w);
  *(ushort4*)(hxbbf + i4) = o;
}
__global__ __launch_bounds__(256) void k_bias(const float* __restrict__ ib1, const float* __restrict__ hb1,
                                              const float* __restrict__ ib2, const float* __restrict__ hb2,
                                              float* __restrict__ b1s, float* __restrict__ b2s){
  int i = blockIdx.x*256 + threadIdx.x;                // 4096
  b1s[i] = ib1[i] + hb1[i];
  b2s[i] = ib2[i] + hb2[i];
}

// ============ prep: pc GEMM (f32 in, bf16 out) ============
__global__ __launch_bounds__(256) void k_pc(const float* __restrict__ ctxp, const float* __restrict__ c2a,
                                            const float* __restrict__ bc, ushort* __restrict__ pcb){
  __shared__ __align__(16) float As[32][68];
  __shared__ __align__(16) float Bs[32][68];
  const int tid = threadIdx.x;
  const int m0 = blockIdx.x * 64;
  const int n0 = blockIdx.y * 64;
  const int tx = tid & 15, ty = tid >> 4;
  float acc[4][4] = {};
  for (int k0 = 0; k0 < 1024; k0 += 32){
#pragma unroll
    for (int l = 0; l < 8; ++l){
      int idx = l*256 + tid; int m = idx >> 5, k = idx & 31;
      As[k][m] = ctxp[(m0+m)*1024 + k0 + k];
    }
#pragma unroll
    for (int l = 0; l < 8; ++l){
      int idx = l*256 + tid; int k = idx >> 6, n = idx & 63;
      Bs[k][n] = c2a[(k0+k)*1024 + n0 + n];
    }
    __syncthreads();
#pragma unroll
    for (int k = 0; k < 32; ++k){
      float4 a4 = *(const float4*)&As[k][4*ty];
      float4 b4 = *(const float4*)&Bs[k][4*tx];
      float av[4] = {a4.x, a4.y, a4.z, a4.w};
      float bv[4] = {b4.x, b4.y, b4.z, b4.w};
#pragma unroll
      for (int i = 0; i < 4; ++i)
#pragma unroll
        for (int j = 0; j < 4; ++j) acc[i][j] = fmaf(av[i], bv[j], acc[i][j]);
    }
    __syncthreads();
  }
#pragma unroll
  for (int i = 0; i < 4; ++i){
    int m = m0 + 4*ty + i;
    int n = n0 + 4*tx;
    ushort4 o;
    o.x = f2bf(acc[i][0] + bc[n]);
    o.y = f2bf(acc[i][1] + bc[n+1]);
    o.z = f2bf(acc[i][2] + bc[n+2]);
    o.w = f2bf(acc[i][3] + bc[n+3]);
    *(ushort4*)(pcb + m*1024 + n) = o;
  }
}

// ============ K_A: gates1 MFMA + LSTM1 pointwise, fused ============
// 64 blocks x 512 thr (8 waves): wave w -> gate g=w&3, K-half kh=w>>2
__global__ __launch_bounds__(512) void k_step1(const ushort* __restrict__ xb, const ushort* __restrict__ hxbf,
                                               const ushort* __restrict__ w1b,
                                               const float* __restrict__ b1s,
                                               const float* __restrict__ cxb,
                                               float* __restrict__ cym, ushort* __restrict__ hybf, int t){
  __shared__ float lds[2][4][64][17];
  const int tid = threadIdx.x;
  const int lane = tid & 63;
  const int w = tid >> 6;
  const int g = w & 3;
  const int kh = w >> 2;
  const int j = blockIdx.x;
  const int ncol = g*1024 + j*16 + (lane & 15);
  const int ko = (lane >> 4) << 3;
  const int arow = lane & 15;
  const ushort* wp = w1b + ncol*1536 + kh*768 + ko;
  f32x4 a0 = {0.f,0.f,0.f,0.f}, a1 = a0, a2 = a0, a3 = a0;
  if (kh == 0){
    const ushort* xp = xb + (t*64 + arow)*512 + ko;
#pragma unroll
    for (int it = 0; it < 16; ++it){
      short8v bf = *(const short8v*)(wp + it*32);
      a0 = MFMA(*(const short8v*)(xp + it*32), bf, a0);
      a1 = MFMA(*(const short8v*)(xp + it*32 + 16*512), bf, a1);
      a2 = MFMA(*(const short8v*)(xp + it*32 + 32*512), bf, a2);
      a3 = MFMA(*(const short8v*)(xp + it*32 + 48*512), bf, a3);
    }
    const ushort* hp = hxbf + arow*1024 + ko;
#pragma unroll
    for (int it = 0; it < 8; ++it){
      short8v bf = *(const short8v*)(wp + (16+it)*32);
      a0 = MFMA(*(const short8v*)(hp + it*32), bf, a0);
      a1 = MFMA(*(const short8v*)(hp + it*32 + 16*1024), bf, a1);
      a2 = MFMA(*(const short8v*)(hp + it*32 + 32*1024), bf, a2);
      a3 = MFMA(*(const short8v*)(hp + it*32 + 48*1024), bf, a3);
    }
  } else {
    const ushort* hp = hxbf + arow*1024 + 256 + ko;
#pragma unroll
    for (int it = 0; it < 24; ++it){
      short8v bf = *(const short8v*)(wp + it*32);
      a0 = MFMA(*(const short8v*)(hp + it*32), bf, a0);
      a1 = MFMA(*(const short8v*)(hp + it*32 + 16*1024), bf, a1);
      a2 = MFMA(*(const short8v*)(hp + it*32 + 32*1024), bf, a2);
      a3 = MFMA(*(const short8v*)(hp + it*32 + 48*1024), bf, a3);
    }
  }
  {
    const int ccol = lane & 15;
    const int rb = (lane >> 4) * 4;
#pragma unroll
    for (int r = 0; r < 4; ++r){
      lds[kh][g][rb + r][ccol]      = a0[r];
      lds[kh][g][16 + rb + r][ccol] = a1[r];
      lds[kh][g][32 + rb + r][ccol] = a2[r];
      lds[kh][g][48 + rb + r][ccol] = a3[r];
    }
  }
  __syncthreads();
  const int e = tid * 2;
  const int row = e >> 4;
  const int c0 = e & 15;
  const int h = j*16 + c0;
#pragma unroll
  for (int u = 0; u < 2; ++u){
    int c = c0 + u, hh = h + u;
    float gi = lds[0][0][row][c] + lds[1][0][row][c] + b1s[hh];
    float gf = lds[0][1][row][c] + lds[1][1][row][c] + b1s[1024+hh];
    float gg = lds[0][2][row][c] + lds[1][2][row][c] + b1s[2048+hh];
    float go = lds[0][3][row][c] + lds[1][3][row][c] + b1s[3072+hh];
    float cc = sigf(gf)*cxb[row*1024 + hh] + sigf(gi)*tanhfast(gg);
    cym[row*1024 + hh] = cc;
    hybf[row*1024 + hh] = f2bf(sigf(go)*tanhfast(cc));
  }
}

// ============ K_B: hyproj MFMA (full K per wave) ============
__global__ __launch_bounds__(256) void k_hyproj(const ushort* __restrict__ hybf, const ushort* __restrict__ w2b,
                                                const ushort* __restrict__ xb, const ushort* __restrict__ i2aT,
                                                float* __restrict__ hyp, int t){
  const int lane = threadIdx.x & 63;
  const int strip = threadIdx.x >> 6;
  const int ntile = blockIdx.x * 16;
  const int ncol = ntile + (lane & 15);
  const int ko = (lane >> 4) << 3;
  const int arow = strip*16 + (lane & 15);
  const ushort* wp = w2b + ncol*1024 + ko;
  const ushort* hp = hybf + arow*1024 + ko;
  f32x4 acc = {0.f,0.f,0.f,0.f};
#pragma unroll
  for (int it = 0; it < 32; ++it)
    acc = MFMA(*(const short8v*)(hp + it*32), *(const short8v*)(wp + it*32), acc);
  if (ntile < 1024){
    const ushort* ip = i2aT + ncol*512 + ko;
    const ushort* xp = xb + (t*64 + arow)*512 + ko;
#pragma unroll
    for (int it = 0; it < 16; ++it)
      acc = MFMA(*(const short8v*)(xp + it*32), *(const short8v*)(ip + it*32), acc);
  }
  float* op = hyp + ncol;
  const int rb = strip*16 + (lane >> 4)*4;
#pragma unroll
  for (int r = 0; r < 4; ++r) op[(rb + r)*5120] = acc[r];
}

// ============ K_C: logits — 1024 blocks (b, s-group-of-16), 4 waves, 4 s per wave ============
__global__ __launch_bounds__(256) void k_logits(const ushort* __restrict__ pcb, const float* __restrict__ hyp,
                                                const float* __restrict__ r2a, float* __restrict__ logits){
  const int b  = blockIdx.x >> 4;
  const int sq = blockIdx.x & 15;
  const int w = threadIdx.x >> 6, lane = threadIdx.x & 63;
  const float* qp = hyp + b*5120 + lane*16;
  const float* rp = r2a + lane*16;
  float q[16], r[16];
#pragma unroll
  for (int i = 0; i < 4; ++i){
    float4 qv = ld4(qp + i*4);
    float4 rv = ld4(rp + i*4);
    q[4*i]=qv.x; q[4*i+1]=qv.y; q[4*i+2]=qv.z; q[4*i+3]=qv.w;
    r[4*i]=rv.x; r[4*i+1]=rv.y; r[4*i+2]=rv.z; r[4*i+3]=rv.w;
  }
#pragma unroll
  for (int pi = 0; pi < 4; ++pi){
    const int s = sq*16 + w*4 + pi;
    const ushort* pp = pcb + (s*64 + b)*1024 + lane*16;
    uint4 v0 = *(const uint4*)pp;
    uint4 v1 = *(const uint4*)(pp + 8);
    float acc;
    acc  = tanhfast(u2f(v0.x << 16)              + q[0])  * r[0];
    acc  = fmaf(tanhfast(u2f(v0.x & 0xffff0000u) + q[1]),  r[1],  acc);
    acc  = fmaf(tanhfast(u2f(v0.y << 16)         + q[2]),  r[2],  acc);
    acc  = fmaf(tanhfast(u2f(v0.y & 0xffff0000u) + q[3]),  r[3],  acc);
    acc  = fmaf(tanhfast(u2f(v0.z << 16)         + q[4]),  r[4],  acc);
    acc  = fmaf(tanhfast(u2f(v0.z & 0xffff0000u) + q[5]),  r[5],  acc);
    acc  = fmaf(tanhfast(u2f(v0.w << 16)         + q[6]),  r[6],  acc);
    acc  = fmaf(tanhfast(u2f(v0.w & 0xffff0000u) + q[7]),  r[7],  acc);
    acc  = fmaf(tanhfast(u2f(v1.x << 16)         + q[8]),  r[8],  acc);
    acc  = fmaf(tanhfast(u2f(v1.x & 0xffff0000u) + q[9]),  r[9],  acc);
    acc  = fmaf(tanhfast(u2f(v1.y << 16)         + q[10]), r[10], acc);
    acc  = fmaf(tanhfast(u2f(v1.y & 0xffff0000u) + q[11]), r[11], acc);
    acc  = fmaf(tanhfast(u2f(v1.z << 16)         + q[12]), r[12], acc);
    acc  = fmaf(tanhfast(u2f(v1.z & 0xffff0000u) + q[13]), r[13], acc);
    acc  = fmaf(tanhfast(u2f(v1.w << 16)         + q[14]), r[14], acc);
    acc  = fmaf(tanhfast(u2f(v1.w & 0xffff0000u) + q[15]), r[15], acc);
#pragma unroll
    for (int off = 32; off; off >>= 1) acc += __shfl_xor(acc, off);
    if (lane == 0) logits[b*256 + s] = acc;
  }
}

// ============ K_D: softmax + weighted-context — 512 blocks (b, 128-c slice) ============
__global__ __launch_bounds__(256) void k_attnout(const float* __restrict__ logits, const ushort* __restrict__ ctxb,
                                                 ushort* __restrict__ wctxbf){
  __shared__ float red[256];
  __shared__ float al[256];
  __shared__ float4 part4[8][32];
  const int b = blockIdx.x >> 3, co = blockIdx.x & 7;
  const int tid = threadIdx.x;
  float l = logits[b*256 + tid];
  red[tid] = l; __syncthreads();
  for (int s = 128; s; s >>= 1){ if (tid < s) red[tid] = fmaxf(red[tid], red[tid+s]); __syncthreads(); }
  float mx = red[0]; __syncthreads();
  float e = __expf(l - mx);
  al[tid] = e; red[tid] = e; __syncthreads();
  for (int s = 128; s; s >>= 1){ if (tid < s) red[tid] += red[tid+s]; __syncthreads(); }
  float inv = rcpf_(red[0]);
  const int ci = tid & 31, sh = tid >> 5;
  const int c = co*128 + ci*4;
  const ushort* cp = ctxb + (b*256 + sh*32)*1024 + c;
  float a0=0.f, a1=0.f, a2=0.f, a3=0.f;
#pragma unroll 8
  for (int s = 0; s < 32; ++s){
    ushort4 v = *(const ushort4*)(cp + s*1024);
    float aw = al[sh*32 + s];
    a0 = fmaf(aw, bf2f(v.x), a0);
    a1 = fmaf(aw, bf2f(v.y), a1);
    a2 = fmaf(aw, bf2f(v.z), a2);
    a3 = fmaf(aw, bf2f(v.w), a3);
  }
  part4[sh][ci] = make_float4(a0, a1, a2, a3);
  __syncthreads();
  if (tid < 128){
    const float* pf = (const float*)part4;
    float s0 = pf[tid] + pf[128+tid] + pf[256+tid] + pf[384+tid]
             + pf[512+tid] + pf[640+tid] + pf[768+tid] + pf[896+tid];
    wctxbf[b*1024 + co*128 + tid] = f2bf(s0 * inv);
  }
}

// ============ K_E: gates2 MFMA + LSTM2 pointwise, fused ============
__global__ __launch_bounds__(512) void k_step2(const ushort* __restrict__ wctxbf, const ushort* __restrict__ w3b,
                                               const float* __restrict__ hyp,
                                               const float* __restrict__ b2s,
                                               const float* __restrict__ cym,
                                               float* __restrict__ out, float* __restrict__ hxb,
                                               ushort* __restrict__ hxbbf, float* __restrict__ cxb, int t){
  __shared__ float lds[2][4][64][17];
  const int tid = threadIdx.x;
  const int lane = tid & 63;
  const int w = tid >> 6;
  const int g = w & 3;
  const int kh = w >> 2;
  const int j = blockIdx.x;
  const int ncol = g*1024 + j*16 + (lane & 15);
  const int ko = (lane >> 4) << 3;
  const int arow = lane & 15;
  const ushort* wp = w3b + ncol*1024 + kh*512 + ko;
  const ushort* ap = wctxbf + arow*1024 + kh*512 + ko;
  f32x4 a0 = {0.f,0.f,0.f,0.f}, a1 = a0, a2 = a0, a3 = a0;
#pragma unroll
  for (int it = 0; it < 16; ++it){
    short8v bf = *(const short8v*)(wp + it*32);
    a0 = MFMA(*(const short8v*)(ap + it*32), bf, a0);
    a1 = MFMA(*(const short8v*)(ap + it*32 + 16*1024), bf, a1);
    a2 = MFMA(*(const short8v*)(ap + it*32 + 32*1024), bf, a2);
    a3 = MFMA(*(const short8v*)(ap + it*32 + 48*1024), bf, a3);
  }
  {
    const int ccol = lane & 15;
    const int rb = (lane >> 4) * 4;
#pragma unroll
    for (int r = 0; r < 4; ++r){
      lds[kh][g][rb + r][ccol]      = a0[r];
      lds[kh][g][16 + rb + r][ccol] = a1[r];
      lds[kh][g][32 + rb + r][ccol] = a2[r];
      lds[kh][g][48 + rb + r][ccol] = a3[r];
    }
  }
  __syncthreads();
  const int e = tid * 2;
  const int row = e >> 4;
  const int c0 = e & 15;
#pragma unroll
  for (int u = 0; u < 2; ++u){
    int c = c0 + u;
    int hh = j*16 + c;
    const float* g2 = hyp + row*5120 + 1024;
    float gi = lds[0][0][row][c] + lds[1][0][row][c] + g2[hh]      + b2s[hh];
    float gf = lds[0][1][row][c] + lds[1][1][row][c] + g2[1024+hh] + b2s[1024+hh];
    float gg = lds[0][2][row][c] + lds[1][2][row][c] + g2[2048+hh] + b2s[2048+hh];
    float go = lds[0][3][row][c] + lds[1][3][row][c] + g2[3072+hh] + b2s[3072+hh];
    float cc = sigf(gf)*cym[row*1024 + hh] + sigf(gi)*tanhfast(gg);
    float hv = sigf(go)*tanhfast(cc);
    out[t*65536 + row*1024 + hh] = hv;
    hxb[row*1024 + hh] = hv;
    cxb[row*1024 + hh] = cc;
    hxbbf[row*1024 + hh] = f2bf(hv);
  }
}

extern "C" void kernel_launch(void* const* d_in, const int* in_sizes, int n_in,
                              void* d_out, int out_size, void* d_ws, size_t ws_size,
                              hipStream_t stream) {
  const float* input = (const float*)d_in[0];
  const float* hx    = (const float*)d_in[1];
  const float* cx    = (const float*)d_in[2];
  const float* ctxp  = (const float*)d_in[3];
  const float* iw1   = (const float*)d_in[4];
  const float* hw1   = (const float*)d_in[5];
  const float* ib1   = (const float*)d_in[6];
  const float* hb1   = (const float*)d_in[7];
  const float* iw2   = (const float*)d_in[8];
  const float* hw2   = (const float*)d_in[9];
  const float* ib2   = (const float*)d_in[10];
  const float* hb2   = (const float*)d_in[11];
  const float* c2a   = (const float*)d_in[12];
  const float* b_c2a = (const float*)d_in[13];
  const float* h2a   = (const float*)d_in[14];
  const float* i2a   = (const float*)d_in[15];
  const float* r2a   = (const float*)d_in[16];
  float* out = (float*)d_out;

  char* base = (char*)d_ws;
  ushort* pcb    = (ushort*)(base);                     // 33,554,432
  ushort* ctxb   = (ushort*)(base + 33554432);          // 33,554,432
  ushort* xb     = (ushort*)(base + 67108864);          // 16,777,216
  ushort* w1b    = (ushort*)(base + 83886080);          // 12,582,912
  ushort* w2b    = (ushort*)(base + 96468992);          // 10,485,760
  ushort* w3b    = (ushort*)(base + 106954752);         //  8,388,608
  ushort* i2aT   = (ushort*)(base + 115343360);         //  1,048,576
  float*  hyp    = (float*)(base + 116391936);          //  1,310,720
  float*  cym    = (float*)(base + 117702656);          //    262,144
  float*  hxb    = (float*)(base + 117964800);          //    262,144
  float*  cxb    = (float*)(base + 118226944);          //    262,144
  ushort* hybf   = (ushort*)(base + 118489088);         //    131,072
  ushort* hxbbf  = (ushort*)(base + 118620160);         //    131,072
  ushort* wctxbf = (ushort*)(base + 118751232);         //    131,072
  float*  logits = (float*)(base + 118882304);          //     65,536
  float*  b1s    = (float*)(base + 118947840);          //     16,384
  float*  b2s    = (float*)(base + 118964224);          //     16,384  (end 118,980,608)

  hipMemcpyAsync(hxb, hx, 262144, hipMemcpyDeviceToDevice, stream);
  hipMemcpyAsync(cxb, cx, 262144, hipMemcpyDeviceToDevice, stream);

  k_cvthx<<<64,   256, 0, stream>>>(hx, hxbbf);
  k_bias<<<16,    256, 0, stream>>>(ib1, hb1, ib2, hb2, b1s, b2s);
  k_w1  <<<6144,  256, 0, stream>>>(iw1, hw1, w1b);
  k_w2  <<<5120,  256, 0, stream>>>(h2a, hw2, w2b);
  k_w3  <<<4096,  256, 0, stream>>>(iw2, w3b);
  k_ctxT<<<16384, 256, 0, stream>>>(ctxp, ctxb);
  k_xb  <<<8192,  256, 0, stream>>>(input, xb);
  k_i2aT<<<2048,  256, 0, stream>>>(i2a, i2aT);
  k_pc  <<<dim3(256,16), 256, 0, stream>>>(ctxp, c2a, b_c2a, pcb);

  for (int t = 0; t < 256; ++t){
    k_step1  <<<64,   512, 0, stream>>>(xb, hxbbf, w1b, b1s, cxb, cym, hybf, t);
    k_hyproj <<<320,  256, 0, stream>>>(hybf, w2b, xb, i2aT, hyp, t);
    k_logits <<<1024, 256, 0, stream>>>(pcb, hyp, r2a, logits);
    k_attnout<<<512,  256, 0, stream>>>(logits, ctxb, wctxbf);
    k_step2  <<<64,   512, 0, stream>>>(wctxbf, w3b, hyp, b2s, cym, out, hxb, hxbbf, cxb, t);
  }

  hipMemcpyAsync(out + 16777216,         hxb, 262144, hipMemcpyDeviceToDevice, stream);
  hipMemcpyAsync(out + 16777216 + 65536, cxb, 262144, hipMemcpyDeviceToDevice, stream);
}